// Round 2
// baseline (651.520 us; speedup 1.0000x reference)
//
#include <hip/hip_runtime.h>
#include <math.h>

#define NB 4
#define NH 32
#define NSQ 2048            // seq len
#define ND 128              // head dim
#define SPLIT 4
#define SCHUNK (NSQ / SPLIT)   // 512
#define RB 32                  // rows per block-iteration
#define NITER (SCHUNK / RB)    // 16
#define NTHR 512

static constexpr size_t OUT_ELEMS = (size_t)NB * NH * NSQ * ND;        // 33554432
static constexpr size_t NS_OFF    = OUT_ELEMS;                         // new_states
static constexpr size_t NZ_OFF    = NS_OFF + (size_t)NB * NH * ND * ND; // new_z

// LDS byte offsets.  Row-major planes [32][136] bf16 (272 B row, 16 B pad);
// transposed planes [128][32] bf16 (64 B row, XOR-swizzled 16 B granules).
#define SQH   0
#define SQL   8704
#define SKH   17408
#define SKL   26112
#define SKTH  34816
#define SKTL  43008
#define VDTH  51200
#define VDTL  59392
#define LZ    67584
#define LGATE 68096
#define LSQZ  68608
#define LSKZ  68736
#define LNZ   68864
static constexpr int LDS_BYTES = 69376;   // < 80 KB -> 2 blocks/CU

typedef __attribute__((ext_vector_type(8))) short short8v;   // 8 x bf16 (4 VGPRs)
typedef __attribute__((ext_vector_type(4))) float f32x4;

#define MFMA16(a, b, c) __builtin_amdgcn_mfma_f32_16x16x32_bf16(a, b, c, 0, 0, 0)

__device__ __forceinline__ float4 elu1(float4 x) {
    // elu(x)+1 : x>0 -> x+1 ; x<=0 -> exp(x)
    float4 r;
    r.x = x.x > 0.f ? x.x + 1.f : __expf(x.x);
    r.y = x.y > 0.f ? x.y + 1.f : __expf(x.y);
    r.z = x.z > 0.f ? x.z + 1.f : __expf(x.z);
    r.w = x.w > 0.f ? x.w + 1.f : __expf(x.w);
    return r;
}

// pk2(x1, x0) -> u32 = [bf16(x0) | bf16(x1)<<16]  (truncated bf16, same as round 1)
__device__ __forceinline__ unsigned int pk2(float x1, float x0) {
    return __builtin_amdgcn_perm(__float_as_uint(x1), __float_as_uint(x0), 0x07060302u);
}
// lo residual: x - bf16_trunc(x)
__device__ __forceinline__ float flo(float x) {
    return x - __uint_as_float(__float_as_uint(x) & 0xFFFF0000u);
}
__device__ __forceinline__ float blo(unsigned int w) { return __uint_as_float(w << 16); }
__device__ __forceinline__ float bhi(unsigned int w) { return __uint_as_float(w & 0xFFFF0000u); }

// 8 fp32 -> hi-frag / lo-frag (bf16x8)
__device__ __forceinline__ void pack8(const float* x, short8v& hi, short8v& lo) {
    union { unsigned int u[4]; short8v s; } H, L;
    #pragma unroll
    for (int d = 0; d < 4; ++d) {
        H.u[d] = pk2(x[2 * d + 1], x[2 * d]);
        L.u[d] = pk2(flo(x[2 * d + 1]), flo(x[2 * d]));
    }
    hi = H.s; lo = L.s;
}

// Pre-init new_states = broadcast(init_mem), new_z = broadcast(init_z); main kernel atomicAdds partials.
extern "C" __global__ void cm_init(const float* __restrict__ mem0,
                                   const float* __restrict__ z0,
                                   float* __restrict__ out) {
    const int NSF4 = NB * NH * ND * ND / 4;  // 524288
    const int NZF4 = NB * NH * ND / 4;       // 4096
    int idx = blockIdx.x * 256 + threadIdx.x;
    if (idx < NSF4) {
        const int per_bh = ND * ND / 4;      // 4096
        int h = (idx / per_bh) % NH;
        int off = idx % per_bh;
        ((float4*)(out + NS_OFF))[idx] = ((const float4*)mem0)[h * per_bh + off];
    } else if (idx < NSF4 + NZF4) {
        int j = idx - NSF4;
        const int per_bh = ND / 4;           // 32
        int h = (j / per_bh) % NH;
        int off = j % per_bh;
        ((float4*)(out + NZ_OFF))[j] = ((const float4*)z0)[h * per_bh + off];
    }
}

extern "C" __global__ void __launch_bounds__(NTHR, 4)
cm_main(const float* __restrict__ q, const float* __restrict__ kin,
        const float* __restrict__ v, const float* __restrict__ attn,
        const float* __restrict__ betas, const float* __restrict__ mem0,
        const float* __restrict__ z0, float* __restrict__ out) {
    extern __shared__ char lds[];
    float* lzf    = (float*)(lds + LZ);
    float* lgatef = (float*)(lds + LGATE);
    float* lsqzf  = (float*)(lds + LSQZ);
    float* lskzf  = (float*)(lds + LSKZ);
    float* lnzf   = (float*)(lds + LNZ);

    const int t   = threadIdx.x;
    const int wg  = blockIdx.x;
    const int cch = wg % SPLIT;
    const int h   = (wg / SPLIT) % NH;
    const int b   = wg / (SPLIT * NH);

    if (t < ND) {
        lzf[t] = z0[h * ND + t];
        float be = betas[h * ND + t];
        lgatef[t] = 1.f / (1.f + __expf(-be));
        lnzf[t] = 0.f;
    }

    const int lane = t & 63;
    const int l15  = lane & 15;     // MFMA: A-row / B-col / C-col
    const int l4   = lane >> 4;     // MFMA: k-group / C row-group
    const int wid  = t >> 6;        // wave 0..7
    const int wr   = wid >> 2;      // row half (16 rows) for GEMM1/2
    const int wc   = wid & 3;       // col quarter for GEMM1/2
    const int cc   = t & 31;        // staging column group (float4)
    const int rg   = (t >> 5) & 7;  // staging row group (4 rows)
    const bool isK = (t < 256);     // waves 0-3 stage k, waves 4-7 stage q

    const size_t bh = (size_t)b * NH + h;
    const float4* q4 = (const float4*)(q   + bh * NSQ * ND);
    const float4* k4 = (const float4*)(kin + bh * NSQ * ND);
    const float*  vf = v    + bh * NSQ * ND;
    const float*  af = attn + bh * NSQ * ND;
    float*        of = out  + bh * NSQ * ND;

    // ---- persistent mem B-fragments in registers (hi/lo split), cols wc*32..+32 ----
    short8v bmh[2][4], bml[2][4];   // [ct][kt]
    {
        const float* mh = mem0 + (size_t)h * ND * ND;
        #pragma unroll
        for (int ct = 0; ct < 2; ++ct) {
            #pragma unroll
            for (int kt = 0; kt < 4; ++kt) {
                const int j  = wc * 32 + ct * 16 + l15;
                const int i0 = kt * 32 + l4 * 8;
                float x[8];
                #pragma unroll
                for (int e = 0; e < 8; ++e) x[e] = mh[(size_t)(i0 + e) * ND + j];
                pack8(x, bmh[ct][kt], bml[ct][kt]);
            }
        }
    }

    f32x4 nsa[8];                   // ns rows wid*16..+16, cols ct*16..+16
    #pragma unroll
    for (int i = 0; i < 8; ++i) nsa[i] = (f32x4){0.f, 0.f, 0.f, 0.f};
    float4 nz = make_float4(0.f, 0.f, 0.f, 0.f);

    const float4* src4 = isK ? k4 : q4;
    const int pb_h = isK ? SKH : SQH;
    const int pb_l = pb_h + 8704;

    __syncthreads();

    for (int blk = 0; blk < NITER; ++blk) {
        const int s0 = cch * SCHUNK + blk * RB;

        // ---- phase A: stage sigma planes (hi/lo bf16) + sk transposed ----
        float sf[4][4];
        #pragma unroll
        for (int m = 0; m < 4; ++m) {
            const int r = rg * 4 + m;
            float4 sv = elu1(src4[(size_t)(s0 + r) * 32 + cc]);
            if (isK) { nz.x += sv.x; nz.y += sv.y; nz.z += sv.z; nz.w += sv.w; }
            *(uint2*)(lds + pb_h + r * 272 + cc * 8) =
                make_uint2(pk2(sv.y, sv.x), pk2(sv.w, sv.z));
            *(uint2*)(lds + pb_l + r * 272 + cc * 8) =
                make_uint2(pk2(flo(sv.y), flo(sv.x)), pk2(flo(sv.w), flo(sv.z)));
            sf[m][0] = sv.x; sf[m][1] = sv.y; sf[m][2] = sv.z; sf[m][3] = sv.w;
        }
        if (isK) {
            // in-thread 4x4 transpose -> skT[d][r], granule-swizzled
            #pragma unroll
            for (int j = 0; j < 4; ++j) {
                const int d  = cc * 4 + j;
                const int pg = (rg >> 1) ^ (((d >> 1) ^ (d >> 4)) & 3);
                const int hf = rg & 1;
                *(uint2*)(lds + SKTH + d * 64 + pg * 16 + hf * 8) =
                    make_uint2(pk2(sf[1][j], sf[0][j]), pk2(sf[3][j], sf[2][j]));
                *(uint2*)(lds + SKTL + d * 64 + pg * 16 + hf * 8) =
                    make_uint2(pk2(flo(sf[1][j]), flo(sf[0][j])), pk2(flo(sf[3][j]), flo(sf[2][j])));
            }
        }
        __syncthreads();

        // ---- phase B: z-dots (wave 0), GEMM1/2 on MFMA, attn/v prefetch ----
        if (t < 64) {
            const int r  = t & 31;
            const int ph = (t < 32) ? SQH : SKH;
            float acc = 0.f;
            #pragma unroll 4
            for (int c = 0; c < 16; ++c) {
                uint4 wh = *(const uint4*)(lds + ph + r * 272 + c * 16);
                uint4 wl = *(const uint4*)(lds + ph + 8704 + r * 272 + c * 16);
                float4 za = *(const float4*)(lds + LZ + c * 32);
                float4 zb = *(const float4*)(lds + LZ + c * 32 + 16);
                acc = fmaf(blo(wh.x) + blo(wl.x), za.x, acc);
                acc = fmaf(bhi(wh.x) + bhi(wl.x), za.y, acc);
                acc = fmaf(blo(wh.y) + blo(wl.y), za.z, acc);
                acc = fmaf(bhi(wh.y) + bhi(wl.y), za.w, acc);
                acc = fmaf(blo(wh.z) + blo(wl.z), zb.x, acc);
                acc = fmaf(bhi(wh.z) + bhi(wl.z), zb.y, acc);
                acc = fmaf(blo(wh.w) + blo(wl.w), zb.z, acc);
                acc = fmaf(bhi(wh.w) + bhi(wl.w), zb.w, acc);
            }
            const float inv = 1.f / acc;
            if (t < 32) lsqzf[r] = inv; else lskzf[r] = inv;
        }

        f32x4 mo[2], rt2[2];
        #pragma unroll
        for (int ct = 0; ct < 2; ++ct) {
            mo[ct]  = (f32x4){0.f, 0.f, 0.f, 0.f};
            rt2[ct] = (f32x4){0.f, 0.f, 0.f, 0.f};
        }
        #pragma unroll
        for (int kt = 0; kt < 4; ++kt) {
            const int ro = (wr * 16 + l15) * 272 + kt * 64 + l4 * 16;
            short8v aqh = *(const short8v*)(lds + SQH + ro);
            short8v aql = *(const short8v*)(lds + SQL + ro);
            short8v akh = *(const short8v*)(lds + SKH + ro);
            short8v akl = *(const short8v*)(lds + SKL + ro);
            #pragma unroll
            for (int ct = 0; ct < 2; ++ct) {
                mo[ct]  = MFMA16(aqh, bmh[ct][kt], mo[ct]);
                mo[ct]  = MFMA16(aql, bmh[ct][kt], mo[ct]);
                mo[ct]  = MFMA16(aqh, bml[ct][kt], mo[ct]);
                rt2[ct] = MFMA16(akh, bmh[ct][kt], rt2[ct]);
                rt2[ct] = MFMA16(akl, bmh[ct][kt], rt2[ct]);
                rt2[ct] = MFMA16(akh, bml[ct][kt], rt2[ct]);
            }
        }
        // prefetch attn/v for the epilogue (latency hides under the barrier)
        float avv[2][4], vvv[2][4];
        #pragma unroll
        for (int ct = 0; ct < 2; ++ct) {
            const int col = wc * 32 + ct * 16 + l15;
            #pragma unroll
            for (int rgi = 0; rgi < 4; ++rgi) {
                const size_t off = (size_t)(s0 + wr * 16 + l4 * 4 + rgi) * ND + col;
                avv[ct][rgi] = af[off];
                vvv[ct][rgi] = vf[off];
            }
        }
        __syncthreads();

        // ---- phase C: out = gate*mo*isq + (1-gate)*attn ; vd -> vdT planes ----
        float isq[4], isk[4];
        #pragma unroll
        for (int rgi = 0; rgi < 4; ++rgi) {
            const int r = wr * 16 + l4 * 4 + rgi;
            isq[rgi] = lsqzf[r];
            isk[rgi] = lskzf[r];
        }
        #pragma unroll
        for (int ct = 0; ct < 2; ++ct) {
            const int col = wc * 32 + ct * 16 + l15;
            const float g = lgatef[col];
            float vdv[4];
            #pragma unroll
            for (int rgi = 0; rgi < 4; ++rgi) {
                const size_t off = (size_t)(s0 + wr * 16 + l4 * 4 + rgi) * ND + col;
                const float av = avv[ct][rgi];
                const float mv = mo[ct][rgi] * isq[rgi];
                of[off] = fmaf(g, mv - av, av);
                vdv[rgi] = fmaf(-isk[rgi], rt2[ct][rgi], vvv[ct][rgi]);
            }
            const int pg = (wr * 2 + (l4 >> 1)) ^ (((col >> 1) ^ (col >> 4)) & 3);
            const int hf = l4 & 1;
            *(uint2*)(lds + VDTH + col * 64 + pg * 16 + hf * 8) =
                make_uint2(pk2(vdv[1], vdv[0]), pk2(vdv[3], vdv[2]));
            *(uint2*)(lds + VDTL + col * 64 + pg * 16 + hf * 8) =
                make_uint2(pk2(flo(vdv[1]), flo(vdv[0])), pk2(flo(vdv[3]), flo(vdv[2])));
        }
        __syncthreads();

        // ---- phase D: GEMM3: ns += sk^T @ vd (K = 32, one MFMA k-step) ----
        {
            const int dA = wid * 16 + l15;
            const int gA = l4 ^ (((dA >> 1) ^ (dA >> 4)) & 3);
            short8v ah = *(const short8v*)(lds + SKTH + dA * 64 + gA * 16);
            short8v al = *(const short8v*)(lds + SKTL + dA * 64 + gA * 16);
            #pragma unroll
            for (int ct = 0; ct < 8; ++ct) {
                const int dB = ct * 16 + l15;
                const int gB = l4 ^ (((dB >> 1) ^ (dB >> 4)) & 3);
                short8v bh = *(const short8v*)(lds + VDTH + dB * 64 + gB * 16);
                short8v bl = *(const short8v*)(lds + VDTL + dB * 64 + gB * 16);
                nsa[ct] = MFMA16(ah, bh, nsa[ct]);
                nsa[ct] = MFMA16(al, bh, nsa[ct]);
                nsa[ct] = MFMA16(ah, bl, nsa[ct]);
            }
        }
        __syncthreads();
    }

    // ---- writeback new_states partials ----
    float* nso = out + NS_OFF + bh * ND * ND;
    #pragma unroll
    for (int ct = 0; ct < 8; ++ct) {
        #pragma unroll
        for (int rgi = 0; rgi < 4; ++rgi) {
            const int i = wid * 16 + l4 * 4 + rgi;
            const int j = ct * 16 + l15;
            atomicAdd(nso + (size_t)i * ND + j, nsa[ct][rgi]);
        }
    }
    // ---- writeback new_z partials (only k-threads accumulated nz) ----
    if (isK) {
        atomicAdd(&lnzf[cc * 4 + 0], nz.x);
        atomicAdd(&lnzf[cc * 4 + 1], nz.y);
        atomicAdd(&lnzf[cc * 4 + 2], nz.z);
        atomicAdd(&lnzf[cc * 4 + 3], nz.w);
    }
    __syncthreads();
    if (t < ND) atomicAdd(out + NZ_OFF + bh * ND + t, lnzf[t]);
}

extern "C" void kernel_launch(void* const* d_in, const int* in_sizes, int n_in,
                              void* d_out, int out_size, void* d_ws, size_t ws_size,
                              hipStream_t stream) {
    const float* q     = (const float*)d_in[0];
    const float* k     = (const float*)d_in[1];
    const float* v     = (const float*)d_in[2];
    const float* attn  = (const float*)d_in[3];
    const float* betas = (const float*)d_in[4];
    const float* mem0  = (const float*)d_in[5];
    const float* z0    = (const float*)d_in[6];
    float* out = (float*)d_out;

    hipFuncSetAttribute((const void*)cm_main,
                        hipFuncAttributeMaxDynamicSharedMemorySize, LDS_BYTES);

    const int initF4 = NB * NH * ND * ND / 4 + NB * NH * ND / 4;  // 528384
    cm_init<<<(initF4 + 255) / 256, 256, 0, stream>>>(mem0, z0, out);
    cm_main<<<NB * NH * SPLIT, NTHR, LDS_BYTES, stream>>>(q, k, v, attn, betas, mem0, z0, out);
}